// Round 4
// baseline (290.173 us; speedup 1.0000x reference)
//
#include <hip/hip_runtime.h>
#include <hip/hip_bf16.h>

#define KS    21
#define H     192
#define W     192
#define OH    172
#define OW    172
#define CROP  10
#define PLANE (H*W)

#define TXD   16
#define TYD   8
#define TILE_W 32
#define TILE_H 8
#define SROWS TILE_H                   // 8 input rows (one kernel row per block)
#define SCOLS (TILE_W + KS - 1)        // 52
#define SCH   (SCOLS / 2)              // 26 (column-parity split)

#define CS    (OH * OW)                // 29584

__device__ __forceinline__ float softplusf_(float x) {
    // stable: max(x,0) + log(1 + exp(-|x|))
    float e = __expf(-fabsf(x));
    return fmaxf(x, 0.0f) + __logf(1.0f + e);
}

__global__ __launch_bounds__(TXD * TYD, 6)   // target <=85 VGPR -> 6 waves/SIMD
void ar_row_kernel(const float* __restrict__ kraw,
                   const float* __restrict__ rad,
                   const float* __restrict__ mask,
                   float* __restrict__ out)
{
    // {mask, r, g, b} per pixel, split by column parity: 16-lane reads are
    // 16B-stride contiguous (conflict-free b128 pattern).
    __shared__ float4 s4[2][SROWS][SCH];

    const int zz = blockIdx.z;             // grid.z = 4*21 = 84
    const int b  = zz & 3;
    const int i  = zz >> 2;                // kernel row 0..20

    const int x0t = blockIdx.x * TILE_W;
    const int y0t = blockIdx.y * TILE_H;
    const int tx  = threadIdx.x, ty = threadIdx.y;
    const int tid = ty * TXD + tx;

    const int x0 = x0t + tx * 2;           // even
    const int y  = y0t + ty;

    // ---- issue this thread's 21 kraw loads FIRST (10.5KB/wave in flight
    // while LDS staging + barrier proceed). All addresses stay inside the
    // [441][192][192] tensor even for edge-overshoot threads.
    const float* kp = kraw + ((size_t)b * KS * KS + (size_t)i * KS) * PLANE
                           + (size_t)(y + CROP) * W + (x0 + CROP);
    float2 kv[KS];
    #pragma unroll
    for (int j = 0; j < KS; ++j)
        kv[j] = *reinterpret_cast<const float2*>(kp + (size_t)j * PLANE);

    // ---- stage mask + radiance rows [y0t+i .. y0t+i+7] (clamped rows/cols
    // only feed out-of-range outputs) ----
    const float* mbase = mask + (size_t)b * PLANE;
    const float* rbase = rad  + (size_t)b * 3 * PLANE;
    for (int t = tid; t < SROWS * SCOLS; t += TXD * TYD) {
        int rr = t / SCOLS, cc = t - rr * SCOLS;
        int gr = min(y0t + i + rr, H - 1);
        int gc = min(x0t + cc, W - 1);
        int off = gr * W + gc;
        float4 v;
        v.x = mbase[off];
        v.y = rbase[off];
        v.z = rbase[off + PLANE];
        v.w = rbase[off + 2 * PLANE];
        s4[cc & 1][rr][cc >> 1] = v;
    }
    __syncthreads();

    float ks0 = 0.f, ks1 = 0.f;
    float a00 = 0.f, a01 = 0.f;
    float a10 = 0.f, a11 = 0.f;
    float a20 = 0.f, a21 = 0.f;

    // rolling window over LDS: cur = pixel col (2tx+j), nxt = col (2tx+j+1)
    float4 cur = s4[0][ty][tx];
    #pragma unroll
    for (int j = 0; j < KS; ++j) {
        float4 nxt = s4[(j + 1) & 1][ty][tx + ((j + 1) >> 1)];
        float s0 = softplusf_(kv[j].x);
        float s1 = softplusf_(kv[j].y);
        float km0 = s0 * cur.x;
        float km1 = s1 * nxt.x;
        ks0 += km0;
        ks1 += km1;
        a00 = fmaf(km0, cur.y, a00);  a01 = fmaf(km1, nxt.y, a01);
        a10 = fmaf(km0, cur.z, a10);  a11 = fmaf(km1, nxt.z, a11);
        a20 = fmaf(km0, cur.w, a20);  a21 = fmaf(km1, nxt.w, a21);
        cur = nxt;
    }

    // ---- accumulate into final output (zeroed by memset each call) ----
    if (y < OH && x0 < OW) {               // x0 even => x0+1 also in range
        const size_t wbase = ((size_t)b * 3 * OH + y) * OW + x0;
        const size_t kbase = (size_t)12 * CS + ((size_t)b * OH + y) * OW + x0;
        atomicAdd(&out[wbase],              a00);
        atomicAdd(&out[wbase + 1],          a01);
        atomicAdd(&out[wbase + CS],         a10);
        atomicAdd(&out[wbase + CS + 1],     a11);
        atomicAdd(&out[wbase + 2 * CS],     a20);
        atomicAdd(&out[wbase + 2 * CS + 1], a21);
        atomicAdd(&out[kbase],              ks0);
        atomicAdd(&out[kbase + 1],          ks1);
    }
}

extern "C" void kernel_launch(void* const* d_in, const int* in_sizes, int n_in,
                              void* d_out, int out_size, void* d_ws, size_t ws_size,
                              hipStream_t stream) {
    const float* kraw = (const float*)d_in[0];   // [4,441,192,192] f32
    const float* rad  = (const float*)d_in[1];   // [4,3,192,192]   f32
    const float* mask = (const float*)d_in[2];   // [4,1,192,192]   f32
    float* out = (float*)d_out;                  // ws[4,3,172,172] ++ ks[4,1,172,172]

    hipMemsetAsync(out, 0, (size_t)out_size * sizeof(float), stream);

    dim3 block(TXD, TYD, 1);
    dim3 grid((OW + TILE_W - 1) / TILE_W, (OH + TILE_H - 1) / TILE_H, 4 * KS);
    hipLaunchKernelGGL(ar_row_kernel, grid, block, 0, stream,
                       kraw, rad, mask, out);
}

// Round 5
// 86.755 us; speedup vs baseline: 3.3447x; 3.3447x over previous
//
#include <hip/hip_runtime.h>
#include <hip/hip_bf16.h>

#define KS    21
#define H     192
#define W     192
#define OH    172
#define OW    172
#define CROP  10
#define PLANE (H*W)

#define NCHUNK 7
#define CROWS  3                       // kernel rows per chunk (7*3=21)

#define TXD   16
#define TYD   8
#define TILE_W 32
#define TILE_H 8
#define SROWS (TILE_H + CROWS - 1)     // 10
#define SCOLS (TILE_W + KS - 1)        // 52
#define SCH   (SCOLS / 2)              // 26 (column-parity split)

#define CS    (OH * OW)                // 29584
#define OUTN  (4 * 4 * OH * OW)        // one partial span = 473344 floats

__device__ __forceinline__ float softplusf_(float x) {
    // stable: max(x,0) + log(1 + exp(-|x|))
    float e = __expf(-fabsf(x));
    return fmaxf(x, 0.0f) + __logf(1.0f + e);
}

// cap 128 VGPR (4 waves/SIMD) but leave ~35 regs of slack over the ~90 live
// so the compiler keeps the 21-load burst hoisted (R4 lesson: a tight cap
// makes it sink loads to uses -> MLP collapses)
__global__ __launch_bounds__(TXD * TYD, 4)
void ar_partial_kernel(const float* __restrict__ kraw,
                       const float* __restrict__ rad,
                       const float* __restrict__ mask,
                       float* __restrict__ part)
{
    // {mask, r, g, b} per pixel, split by column parity: 16-lane reads are
    // 16B-stride contiguous (conflict-free b128 pattern).
    __shared__ float4 s4[2][SROWS][SCH];

    const int zz    = blockIdx.z;          // grid.z = 4*NCHUNK = 28
    const int b     = zz & 3;
    const int chunk = zz >> 2;
    const int i0    = chunk * CROWS;

    const int x0t = blockIdx.x * TILE_W;
    const int y0t = blockIdx.y * TILE_H;
    const int tx  = threadIdx.x, ty = threadIdx.y;
    const int tid = ty * TXD + tx;

    // ---- stage mask + radiance for input rows [y0t+i0 .. y0t+i0+SROWS-1] ----
    const float* mbase = mask + (size_t)b * PLANE;
    const float* rbase = rad  + (size_t)b * 3 * PLANE;
    for (int t = tid; t < SROWS * SCOLS; t += TXD * TYD) {
        int rr = t / SCOLS, cc = t - rr * SCOLS;
        int gr = min(y0t + i0 + rr, H - 1);    // clamped rows/cols only feed
        int gc = min(x0t + cc, W - 1);         // out-of-range outputs
        int off = gr * W + gc;
        float4 v;
        v.x = mbase[off];
        v.y = rbase[off];
        v.z = rbase[off + PLANE];
        v.w = rbase[off + 2 * PLANE];
        s4[cc & 1][rr][cc >> 1] = v;
    }
    __syncthreads();

    const int x0 = x0t + tx * 2;               // even
    const int y  = y0t + ty;

    // all kraw accesses stay inside the [441][192][192] tensor even for
    // edge-overshoot threads (max tap 440, max in-plane offset < 36864);
    // overshoot results are simply not stored.
    const float* kb = kraw + (size_t)b * KS * KS * PLANE
                           + (size_t)(y + CROP) * W + (x0 + CROP);

    float ks0 = 0.f, ks1 = 0.f;
    float a00 = 0.f, a01 = 0.f;
    float a10 = 0.f, a11 = 0.f;
    float a20 = 0.f, a21 = 0.f;

    #pragma unroll 1
    for (int i = 0; i < CROWS; ++i) {
        // hoisted burst: 21 x 512B coalesced loads in flight per wave.
        // Across rows the single buffer self-pipelines: row i+1's kv[j]
        // reload issues as soon as row i's tap j consumed it (WAR release).
        const float* kp = kb + (size_t)(i0 + i) * KS * PLANE;
        float2 kv[KS];
        #pragma unroll
        for (int j = 0; j < KS; ++j)
            kv[j] = *reinterpret_cast<const float2*>(kp + (size_t)j * PLANE);

        const int rr = ty + i;
        // rolling window: cur = pixel col (2tx+j), nxt = col (2tx+j+1)
        float4 cur = s4[0][rr][tx];
        #pragma unroll
        for (int j = 0; j < KS; ++j) {
            float4 nxt = s4[(j + 1) & 1][rr][tx + ((j + 1) >> 1)];
            float s0 = softplusf_(kv[j].x);
            float s1 = softplusf_(kv[j].y);
            float km0 = s0 * cur.x;
            float km1 = s1 * nxt.x;
            ks0 += km0;
            ks1 += km1;
            a00 = fmaf(km0, cur.y, a00);  a01 = fmaf(km1, nxt.y, a01);
            a10 = fmaf(km0, cur.z, a10);  a11 = fmaf(km1, nxt.z, a11);
            a20 = fmaf(km0, cur.w, a20);  a21 = fmaf(km1, nxt.w, a21);
            cur = nxt;
        }
    }

    // ---- store partial, layout mirroring final out, offset by chunk*OUTN ----
    if (y < OH && x0 < OW) {               // x0 even => x0+1 also in range
        float* pb = part + (size_t)chunk * OUTN;
        const size_t wbase = ((size_t)b * 3 * OH + y) * OW + x0;
        const size_t kbase = (size_t)12 * CS + ((size_t)b * OH + y) * OW + x0;
        *reinterpret_cast<float2*>(pb + wbase)          = make_float2(a00, a01);
        *reinterpret_cast<float2*>(pb + wbase + CS)     = make_float2(a10, a11);
        *reinterpret_cast<float2*>(pb + wbase + 2 * CS) = make_float2(a20, a21);
        *reinterpret_cast<float2*>(pb + kbase)          = make_float2(ks0, ks1);
    }
}

__global__ __launch_bounds__(256)
void ar_reduce_kernel(const float* __restrict__ part, float* __restrict__ out)
{
    int i = blockIdx.x * 256 + threadIdx.x;      // over OUTN/4 float4s
    if (i < OUTN / 4) {
        const float4* p4 = reinterpret_cast<const float4*>(part);
        float4 r = p4[i];
        #pragma unroll
        for (int k = 1; k < NCHUNK; ++k) {
            float4 v = p4[i + (size_t)k * (OUTN / 4)];
            r.x += v.x; r.y += v.y; r.z += v.z; r.w += v.w;
        }
        reinterpret_cast<float4*>(out)[i] = r;
    }
}

extern "C" void kernel_launch(void* const* d_in, const int* in_sizes, int n_in,
                              void* d_out, int out_size, void* d_ws, size_t ws_size,
                              hipStream_t stream) {
    const float* kraw = (const float*)d_in[0];   // [4,441,192,192] f32
    const float* rad  = (const float*)d_in[1];   // [4,3,192,192]   f32
    const float* mask = (const float*)d_in[2];   // [4,1,192,192]   f32
    float* out  = (float*)d_out;                 // ws[4,3,172,172] ++ ks[4,1,172,172]
    float* part = (float*)d_ws;                  // NCHUNK partials of OUTN floats

    dim3 block(TXD, TYD, 1);
    dim3 grid((OW + TILE_W - 1) / TILE_W, (OH + TILE_H - 1) / TILE_H, 4 * NCHUNK);
    hipLaunchKernelGGL(ar_partial_kernel, grid, block, 0, stream,
                       kraw, rad, mask, part);

    int n4 = OUTN / 4;
    hipLaunchKernelGGL(ar_reduce_kernel, dim3((n4 + 255) / 256), dim3(256), 0, stream,
                       part, out);
}